// Round 13
// baseline (785.162 us; speedup 1.0000x reference)
//
#include <hip/hip_runtime.h>
#include <math.h>

#define GRID_SZ 128
#define NC 196
#define NC4 49                // NC/4 float4 per row
#define G2 (GRID_SZ*GRID_SZ)  // 16384
#define UPTS 64               // sorted records per wave in reduce pass (divides N)
#define KB 21                 // spatial key bits: gx<<14 | gy<<7 | gz
#define RPW 128               // partial records per wave in reduce_part
#define EMPTYK 0xFFFFFFFFu
#define RECF4 50              // record size: 49 float4 av + (alpha,key,0,0)

// ---------------- wave-aggregated atomic helpers ----------------

__device__ __forceinline__ void agg_hist(int bin, bool valid, int lane,
                                         unsigned int* __restrict__ hist) {
    unsigned long long todo = __ballot(valid);
    while (todo) {
        const int leader = __ffsll((long long)todo) - 1;
        const int lb = __shfl(bin, leader);
        const unsigned long long match = __ballot(valid && bin == lb);
        if (lane == leader) atomicAdd(&hist[lb], (unsigned)__popcll(match));
        todo &= ~match;
    }
}

// ---------------- K1: per-point triple key + histograms ----------------

__global__ __launch_bounds__(256) void key_hist_kernel(
    const float* __restrict__ gs, const float* __restrict__ sb,
    unsigned int* __restrict__ keys, unsigned int* __restrict__ hist21,
    unsigned int* __restrict__ hist, int B, int N) {
    const long long P = (long long)B * N;
    const long long p = (long long)blockIdx.x * blockDim.x + threadIdx.x;
    const bool valid = (p < P);
    const int lane = threadIdx.x & 63;

    int key = -1, bin0 = -1, bin1 = -1, bin2 = -1;
    if (valid) {
        const int b = (int)(p / N);
        const float4 head = *(const float4*)(gs + (size_t)p * NC);

        const float i0 = 1.0f / (sb[1] - sb[0]);
        const float i1 = 1.0f / (sb[3] - sb[2]);
        const float i2 = 1.0f / (sb[5] - sb[4]);
        int gx = (int)((head.x - sb[0]) * i0 * 127.0f);
        int gy = (int)((head.y - sb[2]) * i1 * 127.0f);
        int gz = (int)((head.z - sb[4]) * i2 * 127.0f);
        gx = min(127, max(0, gx));
        gy = min(127, max(0, gy));
        gz = min(127, max(0, gz));

        key = (b << KB) | (gx << 14) | (gy << 7) | gz;
        keys[p] = (unsigned)key;
        bin0 = (b * 3 + 0) * G2 + (gx * GRID_SZ + gy);
        bin1 = (b * 3 + 1) * G2 + (gx * GRID_SZ + gz);
        bin2 = (b * 3 + 2) * G2 + (gy * GRID_SZ + gz);
    }
    agg_hist(key, valid, lane, hist21);
    agg_hist(bin0, valid, lane, hist);
    agg_hist(bin1, valid, lane, hist);
    agg_hist(bin2, valid, lane, hist);
}

// ---------------- K2: fused scans ----------------

__global__ __launch_bounds__(256) void scanAf_kernel(
    const unsigned int* __restrict__ hist21, unsigned int* __restrict__ cur21,
    unsigned int* __restrict__ part1, int n21, int blocks21,
    const unsigned int* __restrict__ hist, int* __restrict__ cid,
    unsigned int* __restrict__ partO, int nO) {
    __shared__ unsigned int s[256];
    const int t = threadIdx.x;
    if ((int)blockIdx.x < blocks21) {
        const int g = blockIdx.x * 256 + t;
        const unsigned v = (g < n21) ? hist21[g] : 0u;
        s[t] = v;
        __syncthreads();
        for (int off = 1; off < 256; off <<= 1) {
            const unsigned u = (t >= off) ? s[t - off] : 0u;
            __syncthreads();
            s[t] += u;
            __syncthreads();
        }
        if (g < n21) cur21[g] = s[t] - v;
        if (t == 255) part1[blockIdx.x] = s[255];
    } else {
        const int blk = (int)blockIdx.x - blocks21;
        const int g = blk * 256 + t;
        const unsigned v = (g < nO && hist[g] > 0u) ? 1u : 0u;
        s[t] = v;
        __syncthreads();
        for (int off = 1; off < 256; off <<= 1) {
            const unsigned u = (t >= off) ? s[t - off] : 0u;
            __syncthreads();
            s[t] += u;
            __syncthreads();
        }
        if (g < nO) cid[g] = (int)(s[t] - v);
        if (t == 255) partO[blk] = s[255];
    }
}

__global__ __launch_bounds__(1024) void scanBf_kernel(
    unsigned int* __restrict__ part1, int n1,
    unsigned int* __restrict__ partO, int nO,
    unsigned int* __restrict__ total) {
    __shared__ unsigned int s[1024];
    const int t = threadIdx.x;
    if (blockIdx.x == 0) {
        unsigned carry = 0;
        for (int base = 0; base < n1; base += 1024) {
            const int g = base + t;
            const unsigned v = (g < n1) ? part1[g] : 0u;
            s[t] = v;
            __syncthreads();
            for (int off = 1; off < 1024; off <<= 1) {
                const unsigned u = (t >= off) ? s[t - off] : 0u;
                __syncthreads();
                s[t] += u;
                __syncthreads();
            }
            if (g < n1) part1[g] = s[t] - v + carry;
            carry += s[1023];
            __syncthreads();
        }
    } else {
        const unsigned v = (t < nO) ? partO[t] : 0u;
        s[t] = v;
        __syncthreads();
        for (int off = 1; off < 1024; off <<= 1) {
            const unsigned u = (t >= off) ? s[t - off] : 0u;
            __syncthreads();
            s[t] += u;
            __syncthreads();
        }
        if (t < nO) partO[t] = s[t] - v;
        if (t == nO - 1 && total != nullptr) *total = s[t];
    }
}

__global__ __launch_bounds__(256) void scanCf_kernel(
    unsigned int* __restrict__ cur21, const unsigned int* __restrict__ part1,
    int n21, int blocks21,
    int* __restrict__ cid, const unsigned int* __restrict__ partO, int nO) {
    const int t = threadIdx.x;
    if ((int)blockIdx.x < blocks21) {
        const int g = blockIdx.x * 256 + t;
        if (g < n21) cur21[g] += part1[blockIdx.x];
    } else {
        const int blk = (int)blockIdx.x - blocks21;
        const int g = blk * 256 + t;
        if (g < nO) cid[g] += (int)partO[blk];
    }
}

// ---------------- zero kernels ----------------

__global__ void zero_kernel(float4* __restrict__ p, long long n4) {
    long long i = (long long)blockIdx.x * blockDim.x + threadIdx.x;
    long long stride = (long long)gridDim.x * blockDim.x;
    const float4 z = make_float4(0.f, 0.f, 0.f, 0.f);
    for (; i < n4; i += stride) p[i] = z;
}

__global__ void zero_dyn_kernel(float4* __restrict__ nwc4, float* __restrict__ dnc,
                                const unsigned int* __restrict__ total) {
    const unsigned T = *total;
    const long long n4 = (long long)T * NC4;
    long long i = (long long)blockIdx.x * blockDim.x + threadIdx.x;
    const long long stride = (long long)gridDim.x * blockDim.x;
    const float4 z = make_float4(0.f, 0.f, 0.f, 0.f);
    for (long long k = i; k < n4; k += stride) nwc4[k] = z;
    for (long long k = i; k < (long long)T; k += stride) dnc[k] = 0.f;
}

// ---------------- K3: streaming-read -> key-sorted record write ----------------
// Wave owns 64 consecutive points. Streaming source read; scattered full-line
// record writes (no read latency exposure). Record: [av x49 f4][alpha,key,0,0].

__global__ __launch_bounds__(256) void sortcopy_kernel(
    const float* __restrict__ gs, const float* __restrict__ sb,
    const unsigned int* __restrict__ keys, unsigned int* __restrict__ cur21,
    float4* __restrict__ rec, long long P) {
    const int lane = threadIdx.x & 63;
    const long long wave = (long long)blockIdx.x * 4 + (threadIdx.x >> 6);
    const long long p0 = wave * 64;
    if (p0 >= P) return;        // P % 64 == 0 -> all waves full

    // phase 1: per-lane sorted destination via aggregated cursor
    const int myKey = (int)keys[p0 + lane];
    unsigned dst = 0;
    {
        unsigned long long todo = ~0ull;
        while (todo) {
            const int leader = __ffsll((long long)todo) - 1;
            const int lk = __shfl(myKey, leader);
            const unsigned long long match = __ballot(myKey == lk);
            unsigned base = 0;
            if (lane == leader) base = atomicAdd(&cur21[lk], (unsigned)__popcll(match));
            base = __shfl((int)base, leader);
            if (myKey == lk) dst = base + (unsigned)__popcll(match & ((1ull << lane) - 1ull));
            todo &= ~match;
        }
    }

    const float lo0 = sb[0], hi0 = sb[1];
    const float lo1 = sb[2], hi1 = sb[3];
    const float lo2 = sb[4], hi2 = sb[5];
    const float s0 = 2.0f / (hi0 - lo0);
    const float s1 = 2.0f / (hi1 - lo1);
    const float s2 = 2.0f / (hi2 - lo2);

    const float4 f40 = make_float4(0.f, 0.f, 0.f, 0.f);
    const bool ld = (lane < NC4);
    const float4* src = (const float4*)gs + (size_t)p0 * NC4;   // streaming

    // phase 2: cooperative copy with depth-1 prefetch
    float4 v = ld ? src[lane] : f40;
    for (int j = 0; j < 64; ++j) {
        const int jn = (j + 1 < 64) ? j + 1 : j;
        float4 vn = ld ? src[(size_t)jn * NC4 + lane] : f40;

        const unsigned dstj = (unsigned)__shfl((int)dst, j);
        const unsigned keyj = (unsigned)__shfl(myKey, j);
        const float hx = __shfl(v.x, 0);
        const float hy = __shfl(v.y, 0);
        const float hz = __shfl(v.z, 0);
        const float hw = __shfl(v.w, 0);

        const float cnx = (hx - lo0) * s0 - 1.0f;
        const float cny = (hy - lo1) * s1 - 1.0f;
        const float cnz = (hz - lo2) * s2 - 1.0f;
        const float alpha = 1.0f / (1.0f + __expf(-hw));

        float4 vv = v;
        if (lane == 0) { vv.x = cnx; vv.y = cny; vv.z = cnz; }
        const float4 av = make_float4(vv.x * alpha, vv.y * alpha,
                                      vv.z * alpha, vv.w * alpha);

        float4* r = rec + (size_t)dstj * RECF4;
        if (ld) r[lane] = av;
        else if (lane == NC4)
            r[NC4] = make_float4(alpha, __uint_as_float(keyj), 0.f, 0.f);

        v = vn;
    }
}

// ---------------- shared flush helpers ----------------

__device__ __forceinline__ void flush3(int key, const int* __restrict__ cid,
                                       const float4& acc, float accD,
                                       float* __restrict__ nwc, float* __restrict__ dnc,
                                       int lane) {
    if (key < 0) return;
    const int b = key >> KB;
    const int gx = (key >> 14) & 127;
    const int gy = (key >> 7) & 127;
    const int gz = key & 127;
    const int cc0 = cid[(b * 3 + 0) * G2 + gx * GRID_SZ + gy];
    const int cc1 = cid[(b * 3 + 1) * G2 + gx * GRID_SZ + gz];
    const int cc2 = cid[(b * 3 + 2) * G2 + gy * GRID_SZ + gz];
    if (lane < NC4) {
        float* b0 = nwc + (size_t)cc0 * NC + 4 * lane;
        float* b1 = nwc + (size_t)cc1 * NC + 4 * lane;
        float* b2 = nwc + (size_t)cc2 * NC + 4 * lane;
        unsafeAtomicAdd(b0 + 0, acc.x); unsafeAtomicAdd(b0 + 1, acc.y);
        unsafeAtomicAdd(b0 + 2, acc.z); unsafeAtomicAdd(b0 + 3, acc.w);
        unsafeAtomicAdd(b1 + 0, acc.x); unsafeAtomicAdd(b1 + 1, acc.y);
        unsafeAtomicAdd(b1 + 2, acc.z); unsafeAtomicAdd(b1 + 3, acc.w);
        unsafeAtomicAdd(b2 + 0, acc.x); unsafeAtomicAdd(b2 + 1, acc.y);
        unsafeAtomicAdd(b2 + 2, acc.z); unsafeAtomicAdd(b2 + 3, acc.w);
    } else if (lane == NC4) {
        unsafeAtomicAdd(dnc + cc0, accD);
        unsafeAtomicAdd(dnc + cc1, accD);
        unsafeAtomicAdd(dnc + cc2, accD);
    }
}

__device__ __forceinline__ void store_partial(long long slot, int key,
                                              const float4& acc, float accD,
                                              unsigned* __restrict__ kpart,
                                              float* __restrict__ apart, int lane) {
    float* base = apart + slot * 200;
    if (lane < NC4) *(float4*)(base + 4 * lane) = acc;
    else if (lane == NC4) base[NC] = accD;
    if (lane == 0) kpart[slot] = (unsigned)key;
}

// ---------------- K4: streaming run-reduce over sorted records --------

__global__ __launch_bounds__(256) void reduce_sorted_kernel(
    const float4* __restrict__ rec, const int* __restrict__ cid,
    float* __restrict__ nwc, float* __restrict__ dnc,
    unsigned* __restrict__ kpart, float* __restrict__ apart, long long P) {
    const int lane = threadIdx.x & 63;
    const long long wave = (long long)blockIdx.x * 4 + (threadIdx.x >> 6);
    const long long i0 = wave * (long long)UPTS;
    if (i0 >= P) return;        // P % UPTS == 0

    const float4 f40 = make_float4(0.f, 0.f, 0.f, 0.f);
    const bool ld = (lane < RECF4);   // lanes 0..49 load record

    const float4* r0 = rec + i0 * RECF4;
    float4 v = ld ? r0[lane] : f40;

    int curKey = -1;
    float4 acc = f40;
    float accD = 0.f;
    bool first = true;

    for (int j = 0; j < UPTS; ++j) {
        const int jn = (j + 1 < UPTS) ? j + 1 : j;
        float4 vn = ld ? r0[(size_t)jn * RECF4 + lane] : f40;

        const float alpha = __shfl(v.x, NC4);
        const int key = __shfl(__float_as_int(v.y), NC4);

        if (key != curKey) {
            if (curKey >= 0) {
                if (first) {
                    store_partial(2 * wave, curKey, acc, accD, kpart, apart, lane);
                    first = false;
                } else {
                    flush3(curKey, cid, acc, accD, nwc, dnc, lane);
                }
            }
            curKey = key; acc = v; accD = alpha;
        } else {
            acc.x += v.x; acc.y += v.y; acc.z += v.z; acc.w += v.w;
            accD += alpha;
        }

        v = vn;
    }
    if (first) {
        store_partial(2 * wave, curKey, acc, accD, kpart, apart, lane);
        if (lane == 0) kpart[2 * wave + 1] = EMPTYK;
    } else {
        store_partial(2 * wave + 1, curKey, acc, accD, kpart, apart, lane);
    }
}

// ---------------- K4b: reduce boundary partials (key-sorted stream) --------

__global__ __launch_bounds__(256) void reduce_part_kernel(
    const unsigned* __restrict__ kpart, const float* __restrict__ apart,
    const int* __restrict__ cid,
    float* __restrict__ nwc, float* __restrict__ dnc, long long S) {
    const int lane = threadIdx.x & 63;
    const long long wave = (long long)blockIdx.x * 4 + (threadIdx.x >> 6);
    const long long r0 = wave * (long long)RPW;
    if (r0 >= S) return;
    long long r1 = r0 + RPW;
    if (r1 > S) r1 = S;

    const float4 f40 = make_float4(0.f, 0.f, 0.f, 0.f);
    int curKey = -1;
    float4 acc = f40;
    float accD = 0.f;

    for (long long r = r0; r < r1; ++r) {
        const unsigned k = kpart[r];
        if (k == EMPTYK) continue;
        const float* base = apart + r * 200;
        float4 rv = (lane < NC4) ? ((const float4*)base)[lane] : f40;
        const float rd = base[NC];
        if ((int)k != curKey) {
            flush3(curKey, cid, acc, accD, nwc, dnc, lane);
            curKey = (int)k; acc = rv; accD = rd;
        } else {
            acc.x += rv.x; acc.y += rv.y; acc.z += rv.z; acc.w += rv.w;
            accD += rd;
        }
    }
    flush3(curKey, cid, acc, accD, nwc, dnc, lane);
}

// ---------------- K5: transpose + normalize from compact ----------------

#define TCELLS 64
__global__ __launch_bounds__(256) void xpose_c_kernel(
    const float* __restrict__ nwc, const float* __restrict__ dnc,
    const int* __restrict__ cid, const unsigned int* __restrict__ hist,
    float* __restrict__ out) {
    __shared__ float tile[TCELLS][197];   // pad: conflict-free column reads
    __shared__ float dinv[TCELLS];
    __shared__ int scid[TCELLS];
    const int t = threadIdx.x;
    const int pg = blockIdx.x >> 8;              // plane index (256 tiles/plane)
    const int c0 = (blockIdx.x & 255) * TCELLS;

    if (t < TCELLS) {
        const int bin = pg * G2 + c0 + t;
        const int cc = (hist[bin] > 0u) ? cid[bin] : -1;
        scid[t] = cc;
        dinv[t] = (cc >= 0) ? 1.0f / fmaxf(dnc[cc], 1e-6f) : 0.0f;
    }
    __syncthreads();

    const float4 f40 = make_float4(0.f, 0.f, 0.f, 0.f);
    for (int i = t; i < TCELLS * NC4; i += 256) {
        const int cell = i / NC4;
        const int cp = i - cell * NC4;
        const int cc = scid[cell];
        float4 v = (cc >= 0) ? ((const float4*)(nwc + (size_t)cc * NC))[cp] : f40;
        float* dst = &tile[cell][cp * 4];
        dst[0] = v.x; dst[1] = v.y; dst[2] = v.z; dst[3] = v.w;
    }
    __syncthreads();

    float* obase = out + (size_t)pg * NC * G2 + c0;
    for (int i = t; i < TCELLS * NC; i += 256) {
        const int c = i >> 6;
        const int cell = i & 63;
        obase[(size_t)c * G2 + cell] = tile[cell][c] * dinv[cell];
    }
}

// ---------------- fallback (direct channel-major, R1-style) ----------------

struct Slot { int tag; float den; float4 acc; };

__device__ __forceinline__ void slot_flush(const Slot& s, float* __restrict__ out,
                                           float* __restrict__ den,
                                           size_t outPlaneBase, int denPlaneBase, int lane) {
    if (s.tag < 0) return;
    if (lane < NC4) {
        size_t base = outPlaneBase + (size_t)(4 * lane) * G2 + (size_t)s.tag;
        unsafeAtomicAdd(out + base,                s.acc.x);
        unsafeAtomicAdd(out + base + (size_t)G2,   s.acc.y);
        unsafeAtomicAdd(out + base + (size_t)2*G2, s.acc.z);
        unsafeAtomicAdd(out + base + (size_t)3*G2, s.acc.w);
    }
    if (lane == 0) unsafeAtomicAdd(den + denPlaneBase + s.tag, s.den);
}

__device__ __forceinline__ void plane_acc(Slot& a, Slot& b, int cell, float alpha,
                                          const float4& av,
                                          float* __restrict__ out, float* __restrict__ den,
                                          size_t outPlaneBase, int denPlaneBase, int lane) {
    if (cell == a.tag) {
        a.acc.x += av.x; a.acc.y += av.y; a.acc.z += av.z; a.acc.w += av.w; a.den += alpha;
    } else if (cell == b.tag) {
        b.acc.x += av.x; b.acc.y += av.y; b.acc.z += av.z; b.acc.w += av.w; b.den += alpha;
    } else {
        if (b.den > a.den) { Slot t = a; a = b; b = t; }
        slot_flush(b, out, den, outPlaneBase, denPlaneBase, lane);
        b.tag = cell; b.den = alpha; b.acc = av;
    }
}

__global__ __launch_bounds__(256) void splat_kernel(
    const float* __restrict__ gs, const float* __restrict__ sb,
    float* __restrict__ out, float* __restrict__ den, int B, int N, int ppw) {
    const int lane = threadIdx.x & 63;
    const long long wave = (long long)blockIdx.x * (blockDim.x >> 6) + (threadIdx.x >> 6);
    const long long totalPts = (long long)B * N;
    long long start = wave * ppw;
    if (start >= totalPts) return;
    long long end = start + ppw;
    if (end > totalPts) end = totalPts;
    const int bb = (int)(start / N);

    const float lo0 = sb[0], hi0 = sb[1];
    const float lo1 = sb[2], hi1 = sb[3];
    const float lo2 = sb[4], hi2 = sb[5];
    const float s0 = 2.0f / (hi0 - lo0);
    const float s1 = 2.0f / (hi1 - lo1);
    const float s2 = 2.0f / (hi2 - lo2);

    const size_t ob0 = ((size_t)(bb * 3 + 0) * NC) * G2;
    const size_t ob1 = ((size_t)(bb * 3 + 1) * NC) * G2;
    const size_t ob2 = ((size_t)(bb * 3 + 2) * NC) * G2;
    const int db0 = (bb * 3 + 0) * G2;
    const int db1 = (bb * 3 + 1) * G2;
    const int db2 = (bb * 3 + 2) * G2;

    const float4 f40 = make_float4(0.f, 0.f, 0.f, 0.f);
    Slot a0{-1,0.f,f40}, t0{-1,0.f,f40}, a1{-1,0.f,f40}, t1{-1,0.f,f40},
         a2{-1,0.f,f40}, t2{-1,0.f,f40};

    const float4* rows = (const float4*)gs;
    const float4* r0 = rows + (size_t)start * NC4;
    float4 v = (lane < NC4) ? r0[lane] : f40;
    float4 h = r0[0];

    for (long long i = start; i < end; ++i) {
        float4 vn = f40, hn = f40;
        if (i + 1 < end) {
            const float4* rn = rows + (size_t)(i + 1) * NC4;
            vn = (lane < NC4) ? rn[lane] : f40;
            hn = rn[0];
        }
        const float cnx = (h.x - lo0) * s0 - 1.0f;
        const float cny = (h.y - lo1) * s1 - 1.0f;
        const float cnz = (h.z - lo2) * s2 - 1.0f;
        int gx = (int)((cnx * 0.5f + 0.5f) * 127.0f);
        int gy = (int)((cny * 0.5f + 0.5f) * 127.0f);
        int gz = (int)((cnz * 0.5f + 0.5f) * 127.0f);
        gx = min(127, max(0, gx)); gy = min(127, max(0, gy)); gz = min(127, max(0, gz));
        const int cxy = __builtin_amdgcn_readfirstlane(gx * GRID_SZ + gy);
        const int cxz = __builtin_amdgcn_readfirstlane(gx * GRID_SZ + gz);
        const int cyz = __builtin_amdgcn_readfirstlane(gy * GRID_SZ + gz);
        const float alpha = 1.0f / (1.0f + __expf(-h.w));
        float4 vv = v;
        if (lane == 0) { vv.x = cnx; vv.y = cny; vv.z = cnz; }
        const float4 av = make_float4(vv.x*alpha, vv.y*alpha, vv.z*alpha, vv.w*alpha);
        plane_acc(a0, t0, cxy, alpha, av, out, den, ob0, db0, lane);
        plane_acc(a1, t1, cxz, alpha, av, out, den, ob1, db1, lane);
        plane_acc(a2, t2, cyz, alpha, av, out, den, ob2, db2, lane);
        v = vn; h = hn;
    }
    slot_flush(a0, out, den, ob0, db0, lane);
    slot_flush(t0, out, den, ob0, db0, lane);
    slot_flush(a1, out, den, ob1, db1, lane);
    slot_flush(t1, out, den, ob1, db1, lane);
    slot_flush(a2, out, den, ob2, db2, lane);
    slot_flush(t2, out, den, ob2, db2, lane);
}

__global__ void normalize_kernel(float* __restrict__ out, const float* __restrict__ den,
                                 int total4) {
    int idx = blockIdx.x * blockDim.x + threadIdx.x;
    const int stride = gridDim.x * blockDim.x;
    for (; idx < total4; idx += stride) {
        float4 v = ((float4*)out)[idx];
        const int e = idx * 4;
        const int cell = e & (G2 - 1);
        const int bp = e / (NC * G2);
        const float4 d = *(const float4*)(den + bp * G2 + cell);
        v.x /= fmaxf(d.x, 1e-6f);
        v.y /= fmaxf(d.y, 1e-6f);
        v.z /= fmaxf(d.z, 1e-6f);
        v.w /= fmaxf(d.w, 1e-6f);
        ((float4*)out)[idx] = v;
    }
}

// ---------------- launch ----------------

extern "C" void kernel_launch(void* const* d_in, const int* in_sizes, int n_in,
                              void* d_out, int out_size, void* d_ws, size_t ws_size,
                              hipStream_t stream) {
    const float* gs = (const float*)d_in[0];
    const float* sb = (const float*)d_in[1];
    float* out = (float*)d_out;

    const int B = out_size / (3 * NC * G2);                            // 4
    const int N = (int)((long long)in_sizes[0] / ((long long)B * NC)); // 131072
    const long long P = (long long)B * N;                              // 524288
    const int NB = B * 3 * G2;                                         // 196608
    const long long NB21 = (long long)B << KB;                         // 8.4M
    const long long gWaves = P / UPTS;                                 // 8192
    const long long S = 2 * gWaves;                                    // 16384 partials

    const size_t nwF = (size_t)NB * NC;
    const size_t dnF = (size_t)NB;
    size_t off = 0;
    const size_t o_nw = off;      off += nwF * 4;
    const size_t o_dn = off;      off += dnF * 4;
    const size_t o_hist21 = off;  off += (size_t)NB21 * 4;   // contiguous with hist
    const size_t o_hist = off;    off += (size_t)NB * 4;
    const size_t o_cur21 = off;   off += (size_t)NB21 * 4;
    const size_t o_cid = off;     off += (size_t)NB * 4;
    const size_t o_part1 = off;   off += ((size_t)NB21 / 256 + 256) * 4;
    const size_t o_partO = off;   off += 1024 * 4;
    const size_t o_total = off;   off += 256;
    const size_t o_keys = off;    off += (size_t)P * 4;
    const size_t o_kpart = off;   off += (size_t)S * 4 + 240;
    const size_t o_apart = off;   off += (size_t)S * 200 * 4;
    const size_t o_rec = off;     off += (size_t)P * RECF4 * 16;
    const size_t need = off;

    const int blocks21 = (int)(NB21 / 256);      // 32768 (NB21 multiple of 256)
    const int nPartO = (NB + 255) / 256;         // 768

    if (ws_size >= need && B <= 64 && nPartO <= 1024 &&
        (N % 64) == 0 && (NB21 % 256) == 0) {
        char* ws = (char*)d_ws;
        float* nwc = (float*)(ws + o_nw);
        float* dnc = (float*)(ws + o_dn);
        unsigned int* hist21 = (unsigned int*)(ws + o_hist21);
        unsigned int* hist = (unsigned int*)(ws + o_hist);
        unsigned int* cur21 = (unsigned int*)(ws + o_cur21);
        int* cid = (int*)(ws + o_cid);
        unsigned int* part1 = (unsigned int*)(ws + o_part1);
        unsigned int* partO = (unsigned int*)(ws + o_partO);
        unsigned int* total = (unsigned int*)(ws + o_total);
        unsigned int* keys = (unsigned int*)(ws + o_keys);
        unsigned int* kpart = (unsigned int*)(ws + o_kpart);
        float* apart = (float*)(ws + o_apart);
        float4* rec = (float4*)(ws + o_rec);

        // zero hist21 + hist (contiguous)
        zero_kernel<<<2048, 256, 0, stream>>>((float4*)hist21,
                                              (NB21 + (long long)NB) / 4);

        const int pBlocks = (int)((P + 255) / 256);                    // 2048
        key_hist_kernel<<<pBlocks, 256, 0, stream>>>(gs, sb, keys, hist21, hist, B, N);

        scanAf_kernel<<<blocks21 + nPartO, 256, 0, stream>>>(
            hist21, cur21, part1, (int)NB21, blocks21, hist, cid, partO, NB);
        scanBf_kernel<<<2, 1024, 0, stream>>>(part1, blocks21, partO, nPartO, total);
        scanCf_kernel<<<blocks21 + nPartO, 256, 0, stream>>>(
            cur21, part1, (int)NB21, blocks21, cid, partO, NB);

        zero_dyn_kernel<<<2048, 256, 0, stream>>>((float4*)nwc, dnc, total);

        const int cBlocks = (int)((P / 64 + 3) / 4);                   // 2048
        sortcopy_kernel<<<cBlocks, 256, 0, stream>>>(gs, sb, keys, cur21, rec, P);

        const int gBlocks = (int)((gWaves + 3) / 4);                   // 2048
        reduce_sorted_kernel<<<gBlocks, 256, 0, stream>>>(rec, cid, nwc, dnc,
                                                          kpart, apart, P);

        const long long rWaves = (S + RPW - 1) / RPW;                  // 128
        const int rBlocks = (int)((rWaves + 3) / 4);                   // 32
        reduce_part_kernel<<<rBlocks, 256, 0, stream>>>(kpart, apart, cid,
                                                        nwc, dnc, S);

        const int xblocks = B * 3 * (G2 / TCELLS);                     // 3072
        xpose_c_kernel<<<xblocks, 256, 0, stream>>>(nwc, dnc, cid, hist, out);
    } else {
        float* den = (float*)d_ws;
        const long long out4 = (long long)out_size / 4;
        const long long den4 = (long long)dnF / 4;
        const int ppw = 64;
        const long long waves = ((long long)B * N) / ppw;
        const int blocks = (int)((waves + 3) / 4);
        zero_kernel<<<2048, 256, 0, stream>>>((float4*)out, out4);
        zero_kernel<<<256, 256, 0, stream>>>((float4*)den, den4);
        splat_kernel<<<blocks, 256, 0, stream>>>(gs, sb, out, den, B, N, ppw);
        normalize_kernel<<<4096, 256, 0, stream>>>(out, den, (int)out4);
    }
}

// Round 14
// 709.866 us; speedup vs baseline: 1.1061x; 1.1061x over previous
//
#include <hip/hip_runtime.h>
#include <math.h>

#define GRID_SZ 128
#define NC 196
#define NC4 49                // NC/4 float4 per row
#define G2 (GRID_SZ*GRID_SZ)  // 16384
#define BPB 64                // blocks per batch in accum
#define SLOTS 128             // LDS table slots (one per gx, gy=gz=0)
#define SLOTF 200             // floats per slot (196 acc + den + pad)

// =========================================================================
// K1: streaming LDS-table accumulation.
// Block = 4 waves, 1 block/CU (100 KB LDS). Wave processes consecutive
// points (fully coalesced scalar loads: ch = lane + 64k). Hot keys
// (gy==0 && gz==0, ~97.7% of points) accumulate into LDS slot gx via
// ds_add_f32 (lane-stride-1 -> 2-way bank alias, free). Tail points flush
// directly to the full per-plane bins with global atomics.
// At block end the table is dumped contention-free to tblout.
// =========================================================================

__global__ __launch_bounds__(256, 1) void lds_accum_kernel(
    const float* __restrict__ gs, const float* __restrict__ sb,
    float* __restrict__ nw, float* __restrict__ dn,
    float* __restrict__ tblout, int N) {
    __shared__ float tbl[SLOTS * SLOTF];   // 102400 B

    const int tid = threadIdx.x;
    const int lane = tid & 63;
    const int widx = tid >> 6;

    for (int i = tid; i < SLOTS * SLOTF; i += 256) tbl[i] = 0.f;
    __syncthreads();

    const int b = blockIdx.x / BPB;
    const int blk = blockIdx.x % BPB;
    const int strip = N / BPB;            // points per block
    const int cnt = strip / 4;            // points per wave
    const long long p0 = (long long)b * N + (long long)blk * strip
                       + (long long)widx * cnt;

    const float lo0 = sb[0], hi0 = sb[1];
    const float lo1 = sb[2], hi1 = sb[3];
    const float lo2 = sb[4], hi2 = sb[5];
    const float s0 = 2.0f / (hi0 - lo0);
    const float s1 = 2.0f / (hi1 - lo1);
    const float s2 = 2.0f / (hi2 - lo2);

    const float* rows = gs + (size_t)p0 * NC;
    const bool l4 = (lane < 4);

    // depth-2 pipeline over scalar channel loads (streaming, unconditional)
    #define LOADP(J, V0, V1, V2, V3)                                   \
        {                                                              \
            const float* r_ = rows + (size_t)(J) * NC;                 \
            V0 = r_[lane];                                             \
            V1 = r_[64 + lane];                                        \
            V2 = r_[128 + lane];                                       \
            V3 = l4 ? r_[192 + lane] : 0.f;                            \
        }

    float a0, a1, a2, a3, b0, b1, b2, b3;
    LOADP(0, a0, a1, a2, a3);
    LOADP((cnt > 1 ? 1 : 0), b0, b1, b2, b3);

    for (int j = 0; j < cnt; ++j) {
        float c0, c1, c2, c3;
        const int jn = (j + 2 < cnt) ? j + 2 : cnt - 1;
        LOADP(jn, c0, c1, c2, c3);

        // head broadcast (channels 0..3 live in lanes 0..3 of a0)
        const float hx = __shfl(a0, 0);
        const float hy = __shfl(a0, 1);
        const float hz = __shfl(a0, 2);
        const float hw = __shfl(a0, 3);

        const float cnx = (hx - lo0) * s0 - 1.0f;
        const float cny = (hy - lo1) * s1 - 1.0f;
        const float cnz = (hz - lo2) * s2 - 1.0f;
        int gx = (int)((cnx * 0.5f + 0.5f) * 127.0f);
        int gy = (int)((cny * 0.5f + 0.5f) * 127.0f);
        int gz = (int)((cnz * 0.5f + 0.5f) * 127.0f);
        gx = min(127, max(0, gx));
        gy = min(127, max(0, gy));
        gz = min(127, max(0, gz));

        const float alpha = 1.0f / (1.0f + __expf(-hw));

        float v0 = a0;
        if (lane == 0) v0 = cnx;
        else if (lane == 1) v0 = cny;
        else if (lane == 2) v0 = cnz;
        const float av0 = v0 * alpha;
        const float av1 = a1 * alpha;
        const float av2 = a2 * alpha;
        const float av3 = a3 * alpha;

        if ((gy | gz) == 0) {
            // hot path: LDS table (wave-uniform slot)
            float* slot = tbl + gx * SLOTF;
            atomicAdd(slot + lane, av0);
            atomicAdd(slot + 64 + lane, av1);
            atomicAdd(slot + 128 + lane, av2);
            if (l4) atomicAdd(slot + 192 + lane, av3);
            if (lane == 4) atomicAdd(slot + 196, alpha);
        } else {
            // tail (~2.3%): direct global atomics to full bins, 3 planes
            const int cells[3] = { gx * GRID_SZ + gy, gx * GRID_SZ + gz,
                                   gy * GRID_SZ + gz };
            #pragma unroll
            for (int p = 0; p < 3; ++p) {
                const int bin = (b * 3 + p) * G2 + cells[p];
                float* dst = nw + (size_t)bin * NC;
                unsafeAtomicAdd(dst + lane, av0);
                unsafeAtomicAdd(dst + 64 + lane, av1);
                unsafeAtomicAdd(dst + 128 + lane, av2);
                if (l4) unsafeAtomicAdd(dst + 192 + lane, av3);
                if (lane == 4) unsafeAtomicAdd(dn + bin, alpha);
            }
        }

        a0 = b0; a1 = b1; a2 = b2; a3 = b3;
        b0 = c0; b1 = c1; b2 = c2; b3 = c3;
    }
    #undef LOADP

    __syncthreads();
    // dump table: record (b,gx) for this block -> tblout[((b*128+s)*BPB+blk)*200+f]
    for (int i = tid; i < SLOTS * SLOTF; i += 256) {
        const int s = i / SLOTF;
        const int f = i - s * SLOTF;
        tblout[(((size_t)b * SLOTS + s) * BPB + blk) * SLOTF + f] = tbl[i];
    }
}

// =========================================================================
// K2: reduce per-block tables -> full bins. Wave w owns (b,gx); reads BPB
// contiguous records (streaming), flushes once to the 3 plane bins.
// =========================================================================

__global__ __launch_bounds__(256) void table_reduce_kernel(
    const float* __restrict__ tblout,
    float* __restrict__ nw, float* __restrict__ dn, int B) {
    const int lane = threadIdx.x & 63;
    const int w = blockIdx.x * 4 + (threadIdx.x >> 6);
    if (w >= B * SLOTS) return;
    const int b = w >> 7;
    const int gx = w & 127;
    const bool l4 = (lane < 4);

    const float* base = tblout + ((size_t)(b * SLOTS + gx) * BPB) * SLOTF;
    float a0 = 0.f, a1 = 0.f, a2 = 0.f, a3 = 0.f, den = 0.f;
    for (int r = 0; r < BPB; ++r) {
        const float* rec = base + (size_t)r * SLOTF;
        a0 += rec[lane];
        a1 += rec[64 + lane];
        a2 += rec[128 + lane];
        if (l4) a3 += rec[192 + lane];
        if (lane == 4) den += rec[196];
    }

    const int cells[3] = { gx * GRID_SZ, gx * GRID_SZ, 0 };
    #pragma unroll
    for (int p = 0; p < 3; ++p) {
        const int bin = (b * 3 + p) * G2 + cells[p];
        float* dst = nw + (size_t)bin * NC;
        unsafeAtomicAdd(dst + lane, a0);
        unsafeAtomicAdd(dst + 64 + lane, a1);
        unsafeAtomicAdd(dst + 128 + lane, a2);
        if (l4) unsafeAtomicAdd(dst + 192 + lane, a3);
        if (lane == 4) unsafeAtomicAdd(dn + bin, den);
    }
}

// =========================================================================
// K3: transpose + normalize (full layout)
// =========================================================================

#define TCELLS 64
__global__ __launch_bounds__(256) void xpose_kernel(const float* __restrict__ nw,
                                                    const float* __restrict__ dn,
                                                    float* __restrict__ out) {
    __shared__ float tile[TCELLS][197];   // pad: conflict-free column reads
    __shared__ float dinv[TCELLS];
    const int t = threadIdx.x;
    const int pg = blockIdx.x >> 8;              // plane index (256 tiles/plane)
    const int c0 = (blockIdx.x & 255) * TCELLS;  // first cell of tile

    const float* src = nw + ((size_t)pg * G2 + c0) * NC;
    for (int i = t; i < TCELLS * NC4; i += 256) {
        const int cell = i / NC4;
        const int cp = i - cell * NC4;
        float4 v = ((const float4*)(src + (size_t)cell * NC))[cp];
        float* dst = &tile[cell][cp * 4];
        dst[0] = v.x; dst[1] = v.y; dst[2] = v.z; dst[3] = v.w;
    }
    if (t < TCELLS) dinv[t] = 1.0f / fmaxf(dn[pg * G2 + c0 + t], 1e-6f);
    __syncthreads();

    float* obase = out + (size_t)pg * NC * G2 + c0;
    for (int i = t; i < TCELLS * NC; i += 256) {
        const int c = i >> 6;
        const int cell = i & 63;
        obase[(size_t)c * G2 + cell] = tile[cell][c] * dinv[cell];
    }
}

// ---------------- utility ----------------

__global__ void zero_kernel(float4* __restrict__ p, long long n4) {
    long long i = (long long)blockIdx.x * blockDim.x + threadIdx.x;
    long long stride = (long long)gridDim.x * blockDim.x;
    const float4 z = make_float4(0.f, 0.f, 0.f, 0.f);
    for (; i < n4; i += stride) p[i] = z;
}

// ---------------- fallback (direct channel-major, R1-style) ----------------

struct Slot { int tag; float den; float4 acc; };

__device__ __forceinline__ void slot_flush(const Slot& s, float* __restrict__ out,
                                           float* __restrict__ den,
                                           size_t outPlaneBase, int denPlaneBase, int lane) {
    if (s.tag < 0) return;
    if (lane < NC4) {
        size_t base = outPlaneBase + (size_t)(4 * lane) * G2 + (size_t)s.tag;
        unsafeAtomicAdd(out + base,                s.acc.x);
        unsafeAtomicAdd(out + base + (size_t)G2,   s.acc.y);
        unsafeAtomicAdd(out + base + (size_t)2*G2, s.acc.z);
        unsafeAtomicAdd(out + base + (size_t)3*G2, s.acc.w);
    }
    if (lane == 0) unsafeAtomicAdd(den + denPlaneBase + s.tag, s.den);
}

__device__ __forceinline__ void plane_acc(Slot& a, Slot& b, int cell, float alpha,
                                          const float4& av,
                                          float* __restrict__ out, float* __restrict__ den,
                                          size_t outPlaneBase, int denPlaneBase, int lane) {
    if (cell == a.tag) {
        a.acc.x += av.x; a.acc.y += av.y; a.acc.z += av.z; a.acc.w += av.w; a.den += alpha;
    } else if (cell == b.tag) {
        b.acc.x += av.x; b.acc.y += av.y; b.acc.z += av.z; b.acc.w += av.w; b.den += alpha;
    } else {
        if (b.den > a.den) { Slot t = a; a = b; b = t; }
        slot_flush(b, out, den, outPlaneBase, denPlaneBase, lane);
        b.tag = cell; b.den = alpha; b.acc = av;
    }
}

__global__ __launch_bounds__(256) void splat_kernel(
    const float* __restrict__ gs, const float* __restrict__ sb,
    float* __restrict__ out, float* __restrict__ den, int B, int N, int ppw) {
    const int lane = threadIdx.x & 63;
    const long long wave = (long long)blockIdx.x * (blockDim.x >> 6) + (threadIdx.x >> 6);
    const long long totalPts = (long long)B * N;
    long long start = wave * ppw;
    if (start >= totalPts) return;
    long long end = start + ppw;
    if (end > totalPts) end = totalPts;
    const int bb = (int)(start / N);

    const float lo0 = sb[0], hi0 = sb[1];
    const float lo1 = sb[2], hi1 = sb[3];
    const float lo2 = sb[4], hi2 = sb[5];
    const float s0 = 2.0f / (hi0 - lo0);
    const float s1 = 2.0f / (hi1 - lo1);
    const float s2 = 2.0f / (hi2 - lo2);

    const size_t ob0 = ((size_t)(bb * 3 + 0) * NC) * G2;
    const size_t ob1 = ((size_t)(bb * 3 + 1) * NC) * G2;
    const size_t ob2 = ((size_t)(bb * 3 + 2) * NC) * G2;
    const int db0 = (bb * 3 + 0) * G2;
    const int db1 = (bb * 3 + 1) * G2;
    const int db2 = (bb * 3 + 2) * G2;

    const float4 f40 = make_float4(0.f, 0.f, 0.f, 0.f);
    Slot a0{-1,0.f,f40}, t0{-1,0.f,f40}, a1{-1,0.f,f40}, t1{-1,0.f,f40},
         a2{-1,0.f,f40}, t2{-1,0.f,f40};

    const float4* rows = (const float4*)gs;
    const float4* r0 = rows + (size_t)start * NC4;
    float4 v = (lane < NC4) ? r0[lane] : f40;
    float4 h = r0[0];

    for (long long i = start; i < end; ++i) {
        float4 vn = f40, hn = f40;
        if (i + 1 < end) {
            const float4* rn = rows + (size_t)(i + 1) * NC4;
            vn = (lane < NC4) ? rn[lane] : f40;
            hn = rn[0];
        }
        const float cnx = (h.x - lo0) * s0 - 1.0f;
        const float cny = (h.y - lo1) * s1 - 1.0f;
        const float cnz = (h.z - lo2) * s2 - 1.0f;
        int gx = (int)((cnx * 0.5f + 0.5f) * 127.0f);
        int gy = (int)((cny * 0.5f + 0.5f) * 127.0f);
        int gz = (int)((cnz * 0.5f + 0.5f) * 127.0f);
        gx = min(127, max(0, gx)); gy = min(127, max(0, gy)); gz = min(127, max(0, gz));
        const int cxy = __builtin_amdgcn_readfirstlane(gx * GRID_SZ + gy);
        const int cxz = __builtin_amdgcn_readfirstlane(gx * GRID_SZ + gz);
        const int cyz = __builtin_amdgcn_readfirstlane(gy * GRID_SZ + gz);
        const float alpha = 1.0f / (1.0f + __expf(-h.w));
        float4 vv = v;
        if (lane == 0) { vv.x = cnx; vv.y = cny; vv.z = cnz; }
        const float4 av = make_float4(vv.x*alpha, vv.y*alpha, vv.z*alpha, vv.w*alpha);
        plane_acc(a0, t0, cxy, alpha, av, out, den, ob0, db0, lane);
        plane_acc(a1, t1, cxz, alpha, av, out, den, ob1, db1, lane);
        plane_acc(a2, t2, cyz, alpha, av, out, den, ob2, db2, lane);
        v = vn; h = hn;
    }
    slot_flush(a0, out, den, ob0, db0, lane);
    slot_flush(t0, out, den, ob0, db0, lane);
    slot_flush(a1, out, den, ob1, db1, lane);
    slot_flush(t1, out, den, ob1, db1, lane);
    slot_flush(a2, out, den, ob2, db2, lane);
    slot_flush(t2, out, den, ob2, db2, lane);
}

__global__ void normalize_kernel(float* __restrict__ out, const float* __restrict__ den,
                                 int total4) {
    int idx = blockIdx.x * blockDim.x + threadIdx.x;
    const int stride = gridDim.x * blockDim.x;
    for (; idx < total4; idx += stride) {
        float4 v = ((float4*)out)[idx];
        const int e = idx * 4;
        const int cell = e & (G2 - 1);
        const int bp = e / (NC * G2);
        const float4 d = *(const float4*)(den + bp * G2 + cell);
        v.x /= fmaxf(d.x, 1e-6f);
        v.y /= fmaxf(d.y, 1e-6f);
        v.z /= fmaxf(d.z, 1e-6f);
        v.w /= fmaxf(d.w, 1e-6f);
        ((float4*)out)[idx] = v;
    }
}

// ---------------- launch ----------------

extern "C" void kernel_launch(void* const* d_in, const int* in_sizes, int n_in,
                              void* d_out, int out_size, void* d_ws, size_t ws_size,
                              hipStream_t stream) {
    const float* gs = (const float*)d_in[0];
    const float* sb = (const float*)d_in[1];
    float* out = (float*)d_out;

    const int B = out_size / (3 * NC * G2);                            // 4
    const int N = (int)((long long)in_sizes[0] / ((long long)B * NC)); // 131072
    const int NB = B * 3 * G2;                                         // 196608

    const size_t nwF = (size_t)NB * NC;                 // 38.5M floats
    const size_t dnF = (size_t)NB;                      // 196K floats
    const size_t tblF = (size_t)B * SLOTS * BPB * SLOTF; // 6.55M floats (26 MB)
    size_t off = 0;
    const size_t o_nw = off;    off += nwF * 4;
    const size_t o_dn = off;    off += dnF * 4;
    const size_t o_tbl = off;   off += tblF * 4;
    const size_t need = off;

    if (ws_size >= need && (N % (BPB * 4)) == 0 && B >= 1) {
        char* ws = (char*)d_ws;
        float* nw = (float*)(ws + o_nw);
        float* dn = (float*)(ws + o_dn);
        float* tblout = (float*)(ws + o_tbl);

        // zero full bins (nw + dn contiguous)
        zero_kernel<<<4096, 256, 0, stream>>>((float4*)nw,
                                              (long long)(nwF + dnF) / 4);

        const int aBlocks = B * BPB;                       // 256
        lds_accum_kernel<<<aBlocks, 256, 0, stream>>>(gs, sb, nw, dn, tblout, N);

        const int rWaves = B * SLOTS;                      // 512
        const int rBlocks = (rWaves + 3) / 4;              // 128
        table_reduce_kernel<<<rBlocks, 256, 0, stream>>>(tblout, nw, dn, B);

        const int xblocks = B * 3 * (G2 / TCELLS);         // 3072
        xpose_kernel<<<xblocks, 256, 0, stream>>>(nw, dn, out);
    } else {
        float* den = (float*)d_ws;
        const long long out4 = (long long)out_size / 4;
        const long long den4 = (long long)dnF / 4;
        const int ppw = 64;
        const long long waves = ((long long)B * N) / ppw;
        const int blocks = (int)((waves + 3) / 4);
        zero_kernel<<<2048, 256, 0, stream>>>((float4*)out, out4);
        zero_kernel<<<256, 256, 0, stream>>>((float4*)den, den4);
        splat_kernel<<<blocks, 256, 0, stream>>>(gs, sb, out, den, B, N, ppw);
        normalize_kernel<<<4096, 256, 0, stream>>>(out, den, (int)out4);
    }
}

// Round 15
// 665.847 us; speedup vs baseline: 1.1792x; 1.0661x over previous
//
#include <hip/hip_runtime.h>
#include <math.h>

#define GRID_SZ 128
#define NC 196
#define NC4 49                // NC/4 float4 per row
#define G2 (GRID_SZ*GRID_SZ)  // 16384
#define BPB 64                // blocks per batch in accum
#define SLOTS 128             // LDS table slots (one per gx, gy=gz=0)
#define SLOTF 200             // floats per slot (196 acc + den + pad)
#define AW 16                 // waves per accum block (1024 threads)

// =========================================================================
// K1: streaming LDS-table accumulation.
// Block = 16 waves (1024 thr), 1 block/CU (100 KB LDS) -> 4 waves/SIMD.
// Wave processes consecutive points (coalesced scalar channel loads:
// ch = lane + 64k). Hot keys (gy==0 && gz==0, ~97.7%) accumulate into LDS
// slot gx (lane-stride-1 -> conflict-free). Tail points flush directly to
// the full per-plane bins with global atomics.
// =========================================================================

__global__ __launch_bounds__(1024, 1) void lds_accum_kernel(
    const float* __restrict__ gs, const float* __restrict__ sb,
    float* __restrict__ nw, float* __restrict__ dn,
    float* __restrict__ tblout, int N) {
    __shared__ float tbl[SLOTS * SLOTF];   // 102400 B

    const int tid = threadIdx.x;
    const int lane = tid & 63;
    const int widx = tid >> 6;

    for (int i = tid; i < SLOTS * SLOTF; i += 1024) tbl[i] = 0.f;
    __syncthreads();

    const int b = blockIdx.x / BPB;
    const int blk = blockIdx.x % BPB;
    const int strip = N / BPB;            // points per block (2048)
    const int cnt = strip / AW;           // points per wave (128)
    const long long p0 = (long long)b * N + (long long)blk * strip
                       + (long long)widx * cnt;

    const float lo0 = sb[0], hi0 = sb[1];
    const float lo1 = sb[2], hi1 = sb[3];
    const float lo2 = sb[4], hi2 = sb[5];
    const float s0 = 2.0f / (hi0 - lo0);
    const float s1 = 2.0f / (hi1 - lo1);
    const float s2 = 2.0f / (hi2 - lo2);

    const float* rows = gs + (size_t)p0 * NC;
    const bool l4 = (lane < 4);

    // depth-2 pipeline over scalar channel loads (streaming, unconditional)
    #define LOADP(J, V0, V1, V2, V3)                                   \
        {                                                              \
            const float* r_ = rows + (size_t)(J) * NC;                 \
            V0 = r_[lane];                                             \
            V1 = r_[64 + lane];                                        \
            V2 = r_[128 + lane];                                       \
            V3 = l4 ? r_[192 + lane] : 0.f;                            \
        }

    float a0, a1, a2, a3, b0, b1, b2, b3;
    LOADP(0, a0, a1, a2, a3);
    LOADP((cnt > 1 ? 1 : 0), b0, b1, b2, b3);

    for (int j = 0; j < cnt; ++j) {
        float c0, c1, c2, c3;
        const int jn = (j + 2 < cnt) ? j + 2 : cnt - 1;
        LOADP(jn, c0, c1, c2, c3);

        // head broadcast (channels 0..3 live in lanes 0..3 of a0)
        const float hx = __shfl(a0, 0);
        const float hy = __shfl(a0, 1);
        const float hz = __shfl(a0, 2);
        const float hw = __shfl(a0, 3);

        const float cnx = (hx - lo0) * s0 - 1.0f;
        const float cny = (hy - lo1) * s1 - 1.0f;
        const float cnz = (hz - lo2) * s2 - 1.0f;
        int gx = (int)((cnx * 0.5f + 0.5f) * 127.0f);
        int gy = (int)((cny * 0.5f + 0.5f) * 127.0f);
        int gz = (int)((cnz * 0.5f + 0.5f) * 127.0f);
        gx = min(127, max(0, gx));
        gy = min(127, max(0, gy));
        gz = min(127, max(0, gz));

        const float alpha = 1.0f / (1.0f + __expf(-hw));

        float v0 = a0;
        if (lane == 0) v0 = cnx;
        else if (lane == 1) v0 = cny;
        else if (lane == 2) v0 = cnz;
        const float av0 = v0 * alpha;
        const float av1 = a1 * alpha;
        const float av2 = a2 * alpha;
        const float av3 = a3 * alpha;

        if ((gy | gz) == 0) {
            // hot path: LDS table (wave-uniform slot, lane-stride-1)
            float* slot = tbl + gx * SLOTF;
            atomicAdd(slot + lane, av0);
            atomicAdd(slot + 64 + lane, av1);
            atomicAdd(slot + 128 + lane, av2);
            if (l4) atomicAdd(slot + 192 + lane, av3);
            if (lane == 4) atomicAdd(slot + 196, alpha);
        } else {
            // tail (~2.3%): direct global atomics to full bins, 3 planes
            const int cells[3] = { gx * GRID_SZ + gy, gx * GRID_SZ + gz,
                                   gy * GRID_SZ + gz };
            #pragma unroll
            for (int p = 0; p < 3; ++p) {
                const int bin = (b * 3 + p) * G2 + cells[p];
                float* dst = nw + (size_t)bin * NC;
                unsafeAtomicAdd(dst + lane, av0);
                unsafeAtomicAdd(dst + 64 + lane, av1);
                unsafeAtomicAdd(dst + 128 + lane, av2);
                if (l4) unsafeAtomicAdd(dst + 192 + lane, av3);
                if (lane == 4) unsafeAtomicAdd(dn + bin, alpha);
            }
        }

        a0 = b0; a1 = b1; a2 = b2; a3 = b3;
        b0 = c0; b1 = c1; b2 = c2; b3 = c3;
    }
    #undef LOADP

    __syncthreads();
    // dump table: record (b,gx) for this block -> tblout[((b*128+s)*BPB+blk)*200+f]
    for (int i = tid; i < SLOTS * SLOTF; i += 1024) {
        const int s = i / SLOTF;
        const int f = i - s * SLOTF;
        tblout[(((size_t)b * SLOTS + s) * BPB + blk) * SLOTF + f] = tbl[i];
    }
}

// =========================================================================
// K2: reduce per-block tables -> full bins. Wave w owns (b,gx); reads BPB
// contiguous records (streaming), flushes once to the 3 plane bins.
// =========================================================================

__global__ __launch_bounds__(256) void table_reduce_kernel(
    const float* __restrict__ tblout,
    float* __restrict__ nw, float* __restrict__ dn, int B) {
    const int lane = threadIdx.x & 63;
    const int w = blockIdx.x * 4 + (threadIdx.x >> 6);
    if (w >= B * SLOTS) return;
    const int b = w >> 7;
    const int gx = w & 127;
    const bool l4 = (lane < 4);

    const float* base = tblout + ((size_t)(b * SLOTS + gx) * BPB) * SLOTF;
    float a0 = 0.f, a1 = 0.f, a2 = 0.f, a3 = 0.f, den = 0.f;
    for (int r = 0; r < BPB; ++r) {
        const float* rec = base + (size_t)r * SLOTF;
        a0 += rec[lane];
        a1 += rec[64 + lane];
        a2 += rec[128 + lane];
        if (l4) a3 += rec[192 + lane];
        if (lane == 4) den += rec[196];
    }

    const int cells[3] = { gx * GRID_SZ, gx * GRID_SZ, 0 };
    #pragma unroll
    for (int p = 0; p < 3; ++p) {
        const int bin = (b * 3 + p) * G2 + cells[p];
        float* dst = nw + (size_t)bin * NC;
        unsafeAtomicAdd(dst + lane, a0);
        unsafeAtomicAdd(dst + 64 + lane, a1);
        unsafeAtomicAdd(dst + 128 + lane, a2);
        if (l4) unsafeAtomicAdd(dst + 192 + lane, a3);
        if (lane == 4) unsafeAtomicAdd(dn + bin, den);
    }
}

// =========================================================================
// K3: transpose + normalize (full layout)
// =========================================================================

#define TCELLS 64
__global__ __launch_bounds__(256) void xpose_kernel(const float* __restrict__ nw,
                                                    const float* __restrict__ dn,
                                                    float* __restrict__ out) {
    __shared__ float tile[TCELLS][197];   // pad: conflict-free column reads
    __shared__ float dinv[TCELLS];
    const int t = threadIdx.x;
    const int pg = blockIdx.x >> 8;              // plane index (256 tiles/plane)
    const int c0 = (blockIdx.x & 255) * TCELLS;  // first cell of tile

    const float* src = nw + ((size_t)pg * G2 + c0) * NC;
    for (int i = t; i < TCELLS * NC4; i += 256) {
        const int cell = i / NC4;
        const int cp = i - cell * NC4;
        float4 v = ((const float4*)(src + (size_t)cell * NC))[cp];
        float* dst = &tile[cell][cp * 4];
        dst[0] = v.x; dst[1] = v.y; dst[2] = v.z; dst[3] = v.w;
    }
    if (t < TCELLS) dinv[t] = 1.0f / fmaxf(dn[pg * G2 + c0 + t], 1e-6f);
    __syncthreads();

    float* obase = out + (size_t)pg * NC * G2 + c0;
    for (int i = t; i < TCELLS * NC; i += 256) {
        const int c = i >> 6;
        const int cell = i & 63;
        obase[(size_t)c * G2 + cell] = tile[cell][c] * dinv[cell];
    }
}

// ---------------- utility ----------------

__global__ void zero_kernel(float4* __restrict__ p, long long n4) {
    long long i = (long long)blockIdx.x * blockDim.x + threadIdx.x;
    long long stride = (long long)gridDim.x * blockDim.x;
    const float4 z = make_float4(0.f, 0.f, 0.f, 0.f);
    for (; i < n4; i += stride) p[i] = z;
}

// ---------------- fallback (direct channel-major, R1-style) ----------------

struct Slot { int tag; float den; float4 acc; };

__device__ __forceinline__ void slot_flush(const Slot& s, float* __restrict__ out,
                                           float* __restrict__ den,
                                           size_t outPlaneBase, int denPlaneBase, int lane) {
    if (s.tag < 0) return;
    if (lane < NC4) {
        size_t base = outPlaneBase + (size_t)(4 * lane) * G2 + (size_t)s.tag;
        unsafeAtomicAdd(out + base,                s.acc.x);
        unsafeAtomicAdd(out + base + (size_t)G2,   s.acc.y);
        unsafeAtomicAdd(out + base + (size_t)2*G2, s.acc.z);
        unsafeAtomicAdd(out + base + (size_t)3*G2, s.acc.w);
    }
    if (lane == 0) unsafeAtomicAdd(den + denPlaneBase + s.tag, s.den);
}

__device__ __forceinline__ void plane_acc(Slot& a, Slot& b, int cell, float alpha,
                                          const float4& av,
                                          float* __restrict__ out, float* __restrict__ den,
                                          size_t outPlaneBase, int denPlaneBase, int lane) {
    if (cell == a.tag) {
        a.acc.x += av.x; a.acc.y += av.y; a.acc.z += av.z; a.acc.w += av.w; a.den += alpha;
    } else if (cell == b.tag) {
        b.acc.x += av.x; b.acc.y += av.y; b.acc.z += av.z; b.acc.w += av.w; b.den += alpha;
    } else {
        if (b.den > a.den) { Slot t = a; a = b; b = t; }
        slot_flush(b, out, den, outPlaneBase, denPlaneBase, lane);
        b.tag = cell; b.den = alpha; b.acc = av;
    }
}

__global__ __launch_bounds__(256) void splat_kernel(
    const float* __restrict__ gs, const float* __restrict__ sb,
    float* __restrict__ out, float* __restrict__ den, int B, int N, int ppw) {
    const int lane = threadIdx.x & 63;
    const long long wave = (long long)blockIdx.x * (blockDim.x >> 6) + (threadIdx.x >> 6);
    const long long totalPts = (long long)B * N;
    long long start = wave * ppw;
    if (start >= totalPts) return;
    long long end = start + ppw;
    if (end > totalPts) end = totalPts;
    const int bb = (int)(start / N);

    const float lo0 = sb[0], hi0 = sb[1];
    const float lo1 = sb[2], hi1 = sb[3];
    const float lo2 = sb[4], hi2 = sb[5];
    const float s0 = 2.0f / (hi0 - lo0);
    const float s1 = 2.0f / (hi1 - lo1);
    const float s2 = 2.0f / (hi2 - lo2);

    const size_t ob0 = ((size_t)(bb * 3 + 0) * NC) * G2;
    const size_t ob1 = ((size_t)(bb * 3 + 1) * NC) * G2;
    const size_t ob2 = ((size_t)(bb * 3 + 2) * NC) * G2;
    const int db0 = (bb * 3 + 0) * G2;
    const int db1 = (bb * 3 + 1) * G2;
    const int db2 = (bb * 3 + 2) * G2;

    const float4 f40 = make_float4(0.f, 0.f, 0.f, 0.f);
    Slot a0{-1,0.f,f40}, t0{-1,0.f,f40}, a1{-1,0.f,f40}, t1{-1,0.f,f40},
         a2{-1,0.f,f40}, t2{-1,0.f,f40};

    const float4* rows = (const float4*)gs;
    const float4* r0 = rows + (size_t)start * NC4;
    float4 v = (lane < NC4) ? r0[lane] : f40;
    float4 h = r0[0];

    for (long long i = start; i < end; ++i) {
        float4 vn = f40, hn = f40;
        if (i + 1 < end) {
            const float4* rn = rows + (size_t)(i + 1) * NC4;
            vn = (lane < NC4) ? rn[lane] : f40;
            hn = rn[0];
        }
        const float cnx = (h.x - lo0) * s0 - 1.0f;
        const float cny = (h.y - lo1) * s1 - 1.0f;
        const float cnz = (h.z - lo2) * s2 - 1.0f;
        int gx = (int)((cnx * 0.5f + 0.5f) * 127.0f);
        int gy = (int)((cny * 0.5f + 0.5f) * 127.0f);
        int gz = (int)((cnz * 0.5f + 0.5f) * 127.0f);
        gx = min(127, max(0, gx)); gy = min(127, max(0, gy)); gz = min(127, max(0, gz));
        const int cxy = __builtin_amdgcn_readfirstlane(gx * GRID_SZ + gy);
        const int cxz = __builtin_amdgcn_readfirstlane(gx * GRID_SZ + gz);
        const int cyz = __builtin_amdgcn_readfirstlane(gy * GRID_SZ + gz);
        const float alpha = 1.0f / (1.0f + __expf(-h.w));
        float4 vv = v;
        if (lane == 0) { vv.x = cnx; vv.y = cny; vv.z = cnz; }
        const float4 av = make_float4(vv.x*alpha, vv.y*alpha, vv.z*alpha, vv.w*alpha);
        plane_acc(a0, t0, cxy, alpha, av, out, den, ob0, db0, lane);
        plane_acc(a1, t1, cxz, alpha, av, out, den, ob1, db1, lane);
        plane_acc(a2, t2, cyz, alpha, av, out, den, ob2, db2, lane);
        v = vn; h = hn;
    }
    slot_flush(a0, out, den, ob0, db0, lane);
    slot_flush(t0, out, den, ob0, db0, lane);
    slot_flush(a1, out, den, ob1, db1, lane);
    slot_flush(t1, out, den, ob1, db1, lane);
    slot_flush(a2, out, den, ob2, db2, lane);
    slot_flush(t2, out, den, ob2, db2, lane);
}

__global__ void normalize_kernel(float* __restrict__ out, const float* __restrict__ den,
                                 int total4) {
    int idx = blockIdx.x * blockDim.x + threadIdx.x;
    const int stride = gridDim.x * blockDim.x;
    for (; idx < total4; idx += stride) {
        float4 v = ((float4*)out)[idx];
        const int e = idx * 4;
        const int cell = e & (G2 - 1);
        const int bp = e / (NC * G2);
        const float4 d = *(const float4*)(den + bp * G2 + cell);
        v.x /= fmaxf(d.x, 1e-6f);
        v.y /= fmaxf(d.y, 1e-6f);
        v.z /= fmaxf(d.z, 1e-6f);
        v.w /= fmaxf(d.w, 1e-6f);
        ((float4*)out)[idx] = v;
    }
}

// ---------------- launch ----------------

extern "C" void kernel_launch(void* const* d_in, const int* in_sizes, int n_in,
                              void* d_out, int out_size, void* d_ws, size_t ws_size,
                              hipStream_t stream) {
    const float* gs = (const float*)d_in[0];
    const float* sb = (const float*)d_in[1];
    float* out = (float*)d_out;

    const int B = out_size / (3 * NC * G2);                            // 4
    const int N = (int)((long long)in_sizes[0] / ((long long)B * NC)); // 131072
    const int NB = B * 3 * G2;                                         // 196608

    const size_t nwF = (size_t)NB * NC;                 // 38.5M floats
    const size_t dnF = (size_t)NB;                      // 196K floats
    const size_t tblF = (size_t)B * SLOTS * BPB * SLOTF; // 6.55M floats (26 MB)
    size_t off = 0;
    const size_t o_nw = off;    off += nwF * 4;
    const size_t o_dn = off;    off += dnF * 4;
    const size_t o_tbl = off;   off += tblF * 4;
    const size_t need = off;

    if (ws_size >= need && (N % (BPB * AW)) == 0 && B >= 1) {
        char* ws = (char*)d_ws;
        float* nw = (float*)(ws + o_nw);
        float* dn = (float*)(ws + o_dn);
        float* tblout = (float*)(ws + o_tbl);

        // zero full bins (nw + dn contiguous)
        zero_kernel<<<4096, 256, 0, stream>>>((float4*)nw,
                                              (long long)(nwF + dnF) / 4);

        const int aBlocks = B * BPB;                       // 256
        lds_accum_kernel<<<aBlocks, 1024, 0, stream>>>(gs, sb, nw, dn, tblout, N);

        const int rWaves = B * SLOTS;                      // 512
        const int rBlocks = (rWaves + 3) / 4;              // 128
        table_reduce_kernel<<<rBlocks, 256, 0, stream>>>(tblout, nw, dn, B);

        const int xblocks = B * 3 * (G2 / TCELLS);         // 3072
        xpose_kernel<<<xblocks, 256, 0, stream>>>(nw, dn, out);
    } else {
        float* den = (float*)d_ws;
        const long long out4 = (long long)out_size / 4;
        const long long den4 = (long long)dnF / 4;
        const int ppw = 64;
        const long long waves = ((long long)B * N) / ppw;
        const int blocks = (int)((waves + 3) / 4);
        zero_kernel<<<2048, 256, 0, stream>>>((float4*)out, out4);
        zero_kernel<<<256, 256, 0, stream>>>((float4*)den, den4);
        splat_kernel<<<blocks, 256, 0, stream>>>(gs, sb, out, den, B, N, ppw);
        normalize_kernel<<<4096, 256, 0, stream>>>(out, den, (int)out4);
    }
}

// Round 16
// 404.823 us; speedup vs baseline: 1.9395x; 1.6448x over previous
//
#include <hip/hip_runtime.h>
#include <math.h>

#define GRID_SZ 128
#define NC 196
#define NC4 49                // NC/4 float4 per row
#define G2 (GRID_SZ*GRID_SZ)  // 16384
#define BPB 64                // blocks per batch in accum
#define SLOTS 128             // LDS table slots (one per gx, gy=gz=0)
#define SLOTF 200             // floats per slot (196 acc + den + pad)
#define AW 16                 // waves per accum block (1024 threads)

// =========================================================================
// K1: streaming accumulation.
// Block = 16 waves (1024 thr), 1 block/CU (100 KB LDS table).
// Hot keys (gy==gz==0, ~97.7% of points):
//   gx==0  (~50%)       -> per-wave REGISTER accumulator (no LDS ops)
//   gx==cache tag       -> per-wave sticky register cache
//   cache miss          -> flush cache slot to LDS table (atomicAdd)
// Tail (~2.3%): direct global atomics to full per-plane bins.
// =========================================================================

__device__ __forceinline__ void lds_flush(float* __restrict__ tbl, int tag,
                                          float v0, float v1, float v2, float v3,
                                          float d, int lane, bool l4) {
    float* slot = tbl + tag * SLOTF;
    atomicAdd(slot + lane, v0);
    atomicAdd(slot + 64 + lane, v1);
    atomicAdd(slot + 128 + lane, v2);
    if (l4) atomicAdd(slot + 192 + lane, v3);
    if (lane == 4) atomicAdd(slot + 196, d);
}

__global__ __launch_bounds__(1024, 1) void lds_accum_kernel(
    const float* __restrict__ gs, const float* __restrict__ sb,
    float* __restrict__ nw, float* __restrict__ dn,
    float* __restrict__ tblout, int N) {
    __shared__ float tbl[SLOTS * SLOTF];   // 102400 B

    const int tid = threadIdx.x;
    const int lane = tid & 63;
    const int widx = tid >> 6;

    for (int i = tid; i < SLOTS * SLOTF; i += 1024) tbl[i] = 0.f;
    __syncthreads();

    const int b = blockIdx.x / BPB;
    const int blk = blockIdx.x % BPB;
    const int strip = N / BPB;            // points per block (2048)
    const int cnt = strip / AW;           // points per wave (128)
    const long long p0 = (long long)b * N + (long long)blk * strip
                       + (long long)widx * cnt;

    const float lo0 = sb[0], hi0 = sb[1];
    const float lo1 = sb[2], hi1 = sb[3];
    const float lo2 = sb[4], hi2 = sb[5];
    const float s0 = 2.0f / (hi0 - lo0);
    const float s1 = 2.0f / (hi1 - lo1);
    const float s2 = 2.0f / (hi2 - lo2);

    const float* rows = gs + (size_t)p0 * NC;
    const bool l4 = (lane < 4);

    // depth-2 pipeline over scalar channel loads (streaming, unconditional)
    #define LOADP(J, V0, V1, V2, V3)                                   \
        {                                                              \
            const float* r_ = rows + (size_t)(J) * NC;                 \
            V0 = r_[lane];                                             \
            V1 = r_[64 + lane];                                        \
            V2 = r_[128 + lane];                                       \
            V3 = l4 ? r_[192 + lane] : 0.f;                            \
        }

    float a0, a1, a2, a3, b0, b1, b2, b3;
    LOADP(0, a0, a1, a2, a3);
    LOADP((cnt > 1 ? 1 : 0), b0, b1, b2, b3);

    // slot-0 register accumulator (gx==0, ~50% of points)
    float z0 = 0.f, z1 = 0.f, z2 = 0.f, z3 = 0.f, zd = 0.f;
    // sticky register cache for other hot rows (gx>0)
    int ctag = -1;
    float c0 = 0.f, c1 = 0.f, c2 = 0.f, c3 = 0.f, cd = 0.f;

    for (int j = 0; j < cnt; ++j) {
        float n0, n1, n2, n3;
        const int jn = (j + 2 < cnt) ? j + 2 : cnt - 1;
        LOADP(jn, n0, n1, n2, n3);

        // head broadcast (channels 0..3 live in lanes 0..3 of a0)
        const float hx = __shfl(a0, 0);
        const float hy = __shfl(a0, 1);
        const float hz = __shfl(a0, 2);
        const float hw = __shfl(a0, 3);

        const float cnx = (hx - lo0) * s0 - 1.0f;
        const float cny = (hy - lo1) * s1 - 1.0f;
        const float cnz = (hz - lo2) * s2 - 1.0f;
        int gx = (int)((cnx * 0.5f + 0.5f) * 127.0f);
        int gy = (int)((cny * 0.5f + 0.5f) * 127.0f);
        int gz = (int)((cnz * 0.5f + 0.5f) * 127.0f);
        gx = min(127, max(0, gx));
        gy = min(127, max(0, gy));
        gz = min(127, max(0, gz));

        const float alpha = 1.0f / (1.0f + __expf(-hw));

        float v0 = a0;
        if (lane == 0) v0 = cnx;
        else if (lane == 1) v0 = cny;
        else if (lane == 2) v0 = cnz;
        const float av0 = v0 * alpha;
        const float av1 = a1 * alpha;
        const float av2 = a2 * alpha;
        const float av3 = a3 * alpha;

        if ((gy | gz) == 0) {
            if (gx == 0) {
                // hottest slot: pure register accumulation
                z0 += av0; z1 += av1; z2 += av2; z3 += av3; zd += alpha;
            } else if (gx == ctag) {
                c0 += av0; c1 += av1; c2 += av2; c3 += av3; cd += alpha;
            } else {
                if (ctag > 0)
                    lds_flush(tbl, ctag, c0, c1, c2, c3, cd, lane, l4);
                ctag = gx;
                c0 = av0; c1 = av1; c2 = av2; c3 = av3; cd = alpha;
            }
        } else {
            // tail (~2.3%): direct global atomics to full bins, 3 planes
            const int cells[3] = { gx * GRID_SZ + gy, gx * GRID_SZ + gz,
                                   gy * GRID_SZ + gz };
            #pragma unroll
            for (int p = 0; p < 3; ++p) {
                const int bin = (b * 3 + p) * G2 + cells[p];
                float* dst = nw + (size_t)bin * NC;
                unsafeAtomicAdd(dst + lane, av0);
                unsafeAtomicAdd(dst + 64 + lane, av1);
                unsafeAtomicAdd(dst + 128 + lane, av2);
                if (l4) unsafeAtomicAdd(dst + 192 + lane, av3);
                if (lane == 4) unsafeAtomicAdd(dn + bin, alpha);
            }
        }

        a0 = b0; a1 = b1; a2 = b2; a3 = b3;
        b0 = n0; b1 = n1; b2 = n2; b3 = n3;
    }
    #undef LOADP

    // final flushes: cache slot, then slot-0 registers
    if (ctag > 0) lds_flush(tbl, ctag, c0, c1, c2, c3, cd, lane, l4);
    lds_flush(tbl, 0, z0, z1, z2, z3, zd, lane, l4);

    __syncthreads();
    // dump table: record (b,gx) for this block -> tblout[((b*128+s)*BPB+blk)*200+f]
    for (int i = tid; i < SLOTS * SLOTF; i += 1024) {
        const int s = i / SLOTF;
        const int f = i - s * SLOTF;
        tblout[(((size_t)b * SLOTS + s) * BPB + blk) * SLOTF + f] = tbl[i];
    }
}

// =========================================================================
// K2: reduce per-block tables -> full bins. Wave w owns (b,gx); reads BPB
// contiguous records (streaming), flushes once to the 3 plane bins.
// =========================================================================

__global__ __launch_bounds__(256) void table_reduce_kernel(
    const float* __restrict__ tblout,
    float* __restrict__ nw, float* __restrict__ dn, int B) {
    const int lane = threadIdx.x & 63;
    const int w = blockIdx.x * 4 + (threadIdx.x >> 6);
    if (w >= B * SLOTS) return;
    const int b = w >> 7;
    const int gx = w & 127;
    const bool l4 = (lane < 4);

    const float* base = tblout + ((size_t)(b * SLOTS + gx) * BPB) * SLOTF;
    float a0 = 0.f, a1 = 0.f, a2 = 0.f, a3 = 0.f, den = 0.f;
    for (int r = 0; r < BPB; ++r) {
        const float* rec = base + (size_t)r * SLOTF;
        a0 += rec[lane];
        a1 += rec[64 + lane];
        a2 += rec[128 + lane];
        if (l4) a3 += rec[192 + lane];
        if (lane == 4) den += rec[196];
    }

    const int cells[3] = { gx * GRID_SZ, gx * GRID_SZ, 0 };
    #pragma unroll
    for (int p = 0; p < 3; ++p) {
        const int bin = (b * 3 + p) * G2 + cells[p];
        float* dst = nw + (size_t)bin * NC;
        unsafeAtomicAdd(dst + lane, a0);
        unsafeAtomicAdd(dst + 64 + lane, a1);
        unsafeAtomicAdd(dst + 128 + lane, a2);
        if (l4) unsafeAtomicAdd(dst + 192 + lane, a3);
        if (lane == 4) unsafeAtomicAdd(dn + bin, den);
    }
}

// =========================================================================
// K3: transpose + normalize (full layout)
// =========================================================================

#define TCELLS 64
__global__ __launch_bounds__(256) void xpose_kernel(const float* __restrict__ nw,
                                                    const float* __restrict__ dn,
                                                    float* __restrict__ out) {
    __shared__ float tile[TCELLS][197];   // pad: conflict-free column reads
    __shared__ float dinv[TCELLS];
    const int t = threadIdx.x;
    const int pg = blockIdx.x >> 8;              // plane index (256 tiles/plane)
    const int c0 = (blockIdx.x & 255) * TCELLS;  // first cell of tile

    const float* src = nw + ((size_t)pg * G2 + c0) * NC;
    for (int i = t; i < TCELLS * NC4; i += 256) {
        const int cell = i / NC4;
        const int cp = i - cell * NC4;
        float4 v = ((const float4*)(src + (size_t)cell * NC))[cp];
        float* dst = &tile[cell][cp * 4];
        dst[0] = v.x; dst[1] = v.y; dst[2] = v.z; dst[3] = v.w;
    }
    if (t < TCELLS) dinv[t] = 1.0f / fmaxf(dn[pg * G2 + c0 + t], 1e-6f);
    __syncthreads();

    float* obase = out + (size_t)pg * NC * G2 + c0;
    for (int i = t; i < TCELLS * NC; i += 256) {
        const int c = i >> 6;
        const int cell = i & 63;
        obase[(size_t)c * G2 + cell] = tile[cell][c] * dinv[cell];
    }
}

// ---------------- utility ----------------

__global__ void zero_kernel(float4* __restrict__ p, long long n4) {
    long long i = (long long)blockIdx.x * blockDim.x + threadIdx.x;
    long long stride = (long long)gridDim.x * blockDim.x;
    const float4 z = make_float4(0.f, 0.f, 0.f, 0.f);
    for (; i < n4; i += stride) p[i] = z;
}

// ---------------- fallback (direct channel-major, R1-style) ----------------

struct Slot { int tag; float den; float4 acc; };

__device__ __forceinline__ void slot_flush(const Slot& s, float* __restrict__ out,
                                           float* __restrict__ den,
                                           size_t outPlaneBase, int denPlaneBase, int lane) {
    if (s.tag < 0) return;
    if (lane < NC4) {
        size_t base = outPlaneBase + (size_t)(4 * lane) * G2 + (size_t)s.tag;
        unsafeAtomicAdd(out + base,                s.acc.x);
        unsafeAtomicAdd(out + base + (size_t)G2,   s.acc.y);
        unsafeAtomicAdd(out + base + (size_t)2*G2, s.acc.z);
        unsafeAtomicAdd(out + base + (size_t)3*G2, s.acc.w);
    }
    if (lane == 0) unsafeAtomicAdd(den + denPlaneBase + s.tag, s.den);
}

__device__ __forceinline__ void plane_acc(Slot& a, Slot& b, int cell, float alpha,
                                          const float4& av,
                                          float* __restrict__ out, float* __restrict__ den,
                                          size_t outPlaneBase, int denPlaneBase, int lane) {
    if (cell == a.tag) {
        a.acc.x += av.x; a.acc.y += av.y; a.acc.z += av.z; a.acc.w += av.w; a.den += alpha;
    } else if (cell == b.tag) {
        b.acc.x += av.x; b.acc.y += av.y; b.acc.z += av.z; b.acc.w += av.w; b.den += alpha;
    } else {
        if (b.den > a.den) { Slot t = a; a = b; b = t; }
        slot_flush(b, out, den, outPlaneBase, denPlaneBase, lane);
        b.tag = cell; b.den = alpha; b.acc = av;
    }
}

__global__ __launch_bounds__(256) void splat_kernel(
    const float* __restrict__ gs, const float* __restrict__ sb,
    float* __restrict__ out, float* __restrict__ den, int B, int N, int ppw) {
    const int lane = threadIdx.x & 63;
    const long long wave = (long long)blockIdx.x * (blockDim.x >> 6) + (threadIdx.x >> 6);
    const long long totalPts = (long long)B * N;
    long long start = wave * ppw;
    if (start >= totalPts) return;
    long long end = start + ppw;
    if (end > totalPts) end = totalPts;
    const int bb = (int)(start / N);

    const float lo0 = sb[0], hi0 = sb[1];
    const float lo1 = sb[2], hi1 = sb[3];
    const float lo2 = sb[4], hi2 = sb[5];
    const float s0 = 2.0f / (hi0 - lo0);
    const float s1 = 2.0f / (hi1 - lo1);
    const float s2 = 2.0f / (hi2 - lo2);

    const size_t ob0 = ((size_t)(bb * 3 + 0) * NC) * G2;
    const size_t ob1 = ((size_t)(bb * 3 + 1) * NC) * G2;
    const size_t ob2 = ((size_t)(bb * 3 + 2) * NC) * G2;
    const int db0 = (bb * 3 + 0) * G2;
    const int db1 = (bb * 3 + 1) * G2;
    const int db2 = (bb * 3 + 2) * G2;

    const float4 f40 = make_float4(0.f, 0.f, 0.f, 0.f);
    Slot a0{-1,0.f,f40}, t0{-1,0.f,f40}, a1{-1,0.f,f40}, t1{-1,0.f,f40},
         a2{-1,0.f,f40}, t2{-1,0.f,f40};

    const float4* rows = (const float4*)gs;
    const float4* r0 = rows + (size_t)start * NC4;
    float4 v = (lane < NC4) ? r0[lane] : f40;
    float4 h = r0[0];

    for (long long i = start; i < end; ++i) {
        float4 vn = f40, hn = f40;
        if (i + 1 < end) {
            const float4* rn = rows + (size_t)(i + 1) * NC4;
            vn = (lane < NC4) ? rn[lane] : f40;
            hn = rn[0];
        }
        const float cnx = (h.x - lo0) * s0 - 1.0f;
        const float cny = (h.y - lo1) * s1 - 1.0f;
        const float cnz = (h.z - lo2) * s2 - 1.0f;
        int gx = (int)((cnx * 0.5f + 0.5f) * 127.0f);
        int gy = (int)((cny * 0.5f + 0.5f) * 127.0f);
        int gz = (int)((cnz * 0.5f + 0.5f) * 127.0f);
        gx = min(127, max(0, gx)); gy = min(127, max(0, gy)); gz = min(127, max(0, gz));
        const int cxy = __builtin_amdgcn_readfirstlane(gx * GRID_SZ + gy);
        const int cxz = __builtin_amdgcn_readfirstlane(gx * GRID_SZ + gz);
        const int cyz = __builtin_amdgcn_readfirstlane(gy * GRID_SZ + gz);
        const float alpha = 1.0f / (1.0f + __expf(-h.w));
        float4 vv = v;
        if (lane == 0) { vv.x = cnx; vv.y = cny; vv.z = cnz; }
        const float4 av = make_float4(vv.x*alpha, vv.y*alpha, vv.z*alpha, vv.w*alpha);
        plane_acc(a0, t0, cxy, alpha, av, out, den, ob0, db0, lane);
        plane_acc(a1, t1, cxz, alpha, av, out, den, ob1, db1, lane);
        plane_acc(a2, t2, cyz, alpha, av, out, den, ob2, db2, lane);
        v = vn; h = hn;
    }
    slot_flush(a0, out, den, ob0, db0, lane);
    slot_flush(t0, out, den, ob0, db0, lane);
    slot_flush(a1, out, den, ob1, db1, lane);
    slot_flush(t1, out, den, ob1, db1, lane);
    slot_flush(a2, out, den, ob2, db2, lane);
    slot_flush(t2, out, den, ob2, db2, lane);
}

__global__ void normalize_kernel(float* __restrict__ out, const float* __restrict__ den,
                                 int total4) {
    int idx = blockIdx.x * blockDim.x + threadIdx.x;
    const int stride = gridDim.x * blockDim.x;
    for (; idx < total4; idx += stride) {
        float4 v = ((float4*)out)[idx];
        const int e = idx * 4;
        const int cell = e & (G2 - 1);
        const int bp = e / (NC * G2);
        const float4 d = *(const float4*)(den + bp * G2 + cell);
        v.x /= fmaxf(d.x, 1e-6f);
        v.y /= fmaxf(d.y, 1e-6f);
        v.z /= fmaxf(d.z, 1e-6f);
        v.w /= fmaxf(d.w, 1e-6f);
        ((float4*)out)[idx] = v;
    }
}

// ---------------- launch ----------------

extern "C" void kernel_launch(void* const* d_in, const int* in_sizes, int n_in,
                              void* d_out, int out_size, void* d_ws, size_t ws_size,
                              hipStream_t stream) {
    const float* gs = (const float*)d_in[0];
    const float* sb = (const float*)d_in[1];
    float* out = (float*)d_out;

    const int B = out_size / (3 * NC * G2);                            // 4
    const int N = (int)((long long)in_sizes[0] / ((long long)B * NC)); // 131072
    const int NB = B * 3 * G2;                                         // 196608

    const size_t nwF = (size_t)NB * NC;                 // 38.5M floats
    const size_t dnF = (size_t)NB;                      // 196K floats
    const size_t tblF = (size_t)B * SLOTS * BPB * SLOTF; // 6.55M floats (26 MB)
    size_t off = 0;
    const size_t o_nw = off;    off += nwF * 4;
    const size_t o_dn = off;    off += dnF * 4;
    const size_t o_tbl = off;   off += tblF * 4;
    const size_t need = off;

    if (ws_size >= need && (N % (BPB * AW)) == 0 && B >= 1) {
        char* ws = (char*)d_ws;
        float* nw = (float*)(ws + o_nw);
        float* dn = (float*)(ws + o_dn);
        float* tblout = (float*)(ws + o_tbl);

        // zero full bins (nw + dn contiguous)
        zero_kernel<<<4096, 256, 0, stream>>>((float4*)nw,
                                              (long long)(nwF + dnF) / 4);

        const int aBlocks = B * BPB;                       // 256
        lds_accum_kernel<<<aBlocks, 1024, 0, stream>>>(gs, sb, nw, dn, tblout, N);

        const int rWaves = B * SLOTS;                      // 512
        const int rBlocks = (rWaves + 3) / 4;              // 128
        table_reduce_kernel<<<rBlocks, 256, 0, stream>>>(tblout, nw, dn, B);

        const int xblocks = B * 3 * (G2 / TCELLS);         // 3072
        xpose_kernel<<<xblocks, 256, 0, stream>>>(nw, dn, out);
    } else {
        float* den = (float*)d_ws;
        const long long out4 = (long long)out_size / 4;
        const long long den4 = (long long)dnF / 4;
        const int ppw = 64;
        const long long waves = ((long long)B * N) / ppw;
        const int blocks = (int)((waves + 3) / 4);
        zero_kernel<<<2048, 256, 0, stream>>>((float4*)out, out4);
        zero_kernel<<<256, 256, 0, stream>>>((float4*)den, den4);
        splat_kernel<<<blocks, 256, 0, stream>>>(gs, sb, out, den, B, N, ppw);
        normalize_kernel<<<4096, 256, 0, stream>>>(out, den, (int)out4);
    }
}